// Round 13
// baseline (518.282 us; speedup 1.0000x reference)
//
#include <hip/hip_runtime.h>
#include <math.h>

// Problem constants (fixed by setup_inputs): B=8, N=M=8192, D=3, fp32.
// Two-pass MFMA chamfer with SYMMETRIC packed encoding:
//   Aform(u) = [hx,hx,lx, hy,hy,ly, hz,hz,lz, hw,lw, 1,1, 0,0,0]   (u, |u|^2)
//   Bform(v) = [Hx,Lx,Hx, Hy,Ly,Hy, Hz,Lz,Hz, 1,1, hw,lw, 0,0,0]   (of -2v, |v|^2)
// so dot(Aform(u),Bform(v)) = |u|^2 + |v|^2 - 2 u.v = d^2(u,v)  (bf16 hi/lo
// split; dropped lo*lo terms ~2^-32 rel). Pass 1: mfma(Aform(pred),Bform(tgt))
// -> row-min over targets = rk. Pass 2: mfma(Bform(tgt),Aform(pred)) -> row-min
// over preds = ck. SAME two arrays, operands swapped; both passes are the
// minimal loop (MFMA + 16 fmin, no LDS, no col epilogue).
#define BB 8
#define NPTS 8192
#define NSIDE (BB * NPTS)     // 65536 points per side

#define BLOCK 256
#define TCH 4                 // target chunks per batch-dir
#define TCHUNK (NPTS / TCH)   // 2048
#define NTILES (TCHUNK / 32)  // 64 tiles per wave
#define ROWSB 128             // rows per block (4 waves x 32)
#define NRB (NPTS / ROWSB)    // 64 row-blocks
#define TOTALBLK (TCH * NRB * 16)   // 4096

#define INF_KEY 0x7F7F7F7F

typedef short bf16x8 __attribute__((ext_vector_type(8)));
typedef float f32x16 __attribute__((ext_vector_type(16)));

__device__ __forceinline__ int enc_key(float v) {
    int b = __float_as_int(v);
    return b >= 0 ? b : (b ^ 0x7fffffff);
}
__device__ __forceinline__ float dec_key(int k) {
    int b = k >= 0 ? k : (k ^ 0x7fffffff);
    return __int_as_float(b);
}
__device__ __forceinline__ unsigned short f2bf(float f) {   // RNE fp32->bf16
    unsigned u = __float_as_uint(f);
    return (unsigned short)((u + 0x7FFFu + ((u >> 16) & 1u)) >> 16);
}
__device__ __forceinline__ float bfhi(float f, unsigned short* bits) {
    unsigned short h = f2bf(f);
    *bits = h;
    return __uint_as_float(((unsigned)h) << 16);
}
__device__ __forceinline__ void pack16(unsigned short* dst, const unsigned short* s) {
    uint4* d4 = (uint4*)dst;
    uint4 w0 = {(unsigned)s[0] | ((unsigned)s[1] << 16),
                (unsigned)s[2] | ((unsigned)s[3] << 16),
                (unsigned)s[4] | ((unsigned)s[5] << 16),
                (unsigned)s[6] | ((unsigned)s[7] << 16)};
    uint4 w1 = {(unsigned)s[8] | ((unsigned)s[9] << 16),
                (unsigned)s[10] | ((unsigned)s[11] << 16),
                (unsigned)s[12] | ((unsigned)s[13] << 16),
                (unsigned)s[14] | ((unsigned)s[15] << 16)};
    d4[0] = w0; d4[1] = w1;
}

__global__ __launch_bounds__(BLOCK) void chamfer_pack(
        const float* __restrict__ pred, const float* __restrict__ tgt,
        unsigned short* __restrict__ pA, unsigned short* __restrict__ pB,
        int* __restrict__ rk, int* __restrict__ ck,
        float* __restrict__ out, int* __restrict__ done) {
    int i = blockIdx.x * BLOCK + threadIdx.x;      // 0..NSIDE-1
    const unsigned short one = 0x3F80;             // bf16(1.0)
    {   // Aform from pred: raw coords + |p|^2
        float x = pred[(size_t)i * 3 + 0], y = pred[(size_t)i * 3 + 1],
              z = pred[(size_t)i * 3 + 2];
        float w = fmaf(x, x, fmaf(y, y, z * z));
        unsigned short hx, hy, hz, hw;
        float fx = bfhi(x, &hx), fy = bfhi(y, &hy), fz = bfhi(z, &hz);
        float fw = bfhi(w, &hw);
        unsigned short lx = f2bf(x - fx), ly = f2bf(y - fy),
                       lz = f2bf(z - fz), lw = f2bf(w - fw);
        unsigned short s[16] = {hx, hx, lx, hy, hy, ly, hz, hz, lz,
                                hw, lw, one, one, 0, 0, 0};
        pack16(pA + (size_t)i * 16, s);
    }
    {   // Bform from tgt: coords scaled by -2 + |t|^2
        float x = tgt[(size_t)i * 3 + 0], y = tgt[(size_t)i * 3 + 1],
              z = tgt[(size_t)i * 3 + 2];
        float w = fmaf(x, x, fmaf(y, y, z * z));
        float ux = -2.0f * x, uy = -2.0f * y, uz = -2.0f * z;
        unsigned short hx, hy, hz, hw;
        float fx = bfhi(ux, &hx), fy = bfhi(uy, &hy), fz = bfhi(uz, &hz);
        float fw = bfhi(w, &hw);
        unsigned short lx = f2bf(ux - fx), ly = f2bf(uy - fy),
                       lz = f2bf(uz - fz), lw = f2bf(w - fw);
        unsigned short s[16] = {hx, lx, hx, hy, ly, hy, hz, lz, hz,
                                one, one, hw, lw, 0, 0, 0};
        pack16(pB + (size_t)i * 16, s);
    }
    rk[i] = INF_KEY;
    ck[i] = INF_KEY;
    if (i < BB) out[i] = 0.0f;
    if (i == 0) *done = 0;
}

// grid = (TCH, NRB, 16); z: dir = z>>3, batch = z&7. dir0: D=d^2(pred_r,tgt_c),
// row-min -> rk. dir1: operands swapped -> D=d^2(tgt_r,pred_c), row-min -> ck.
// Fragment mapping (HW-verified R9): operand lane l supplies point (l&31),
// K-slots 8*(l>>5)+e. D: col=l&31, row=(k&3)+8*(k>>2)+4*(l>>5).
// Last-arriving block performs the finalize (device-scope counter + fences).
__global__ __launch_bounds__(BLOCK) void chamfer_mm(
        const unsigned short* __restrict__ pA, const unsigned short* __restrict__ pB,
        int* __restrict__ rk, int* __restrict__ ck,
        float* __restrict__ out, int* __restrict__ done) {
    const int dir = blockIdx.z >> 3;
    const int b = blockIdx.z & 7;
    const int tb0 = blockIdx.x * TCHUNK;
    const int rb0 = blockIdx.y * ROWSB;
    const int wave = threadIdx.x >> 6;
    const int lane = threadIdx.x & 63;
    const int lp = lane & 31;
    const int kh = lane >> 5;

    const bf16x8* Aarr = (const bf16x8*)(dir ? pB : pA);
    const bf16x8* Barr = (const bf16x8*)(dir ? pA : pB);
    int* keys = dir ? ck : rk;

    const bf16x8 afrag = Aarr[(size_t)(b * NPTS + rb0 + wave * 32 + lp) * 2 + kh];
    const bf16x8* bp = Barr + (size_t)(b * NPTS + tb0 + lp) * 2 + kh;

    f32x16 zerov;
    #pragma unroll
    for (int k = 0; k < 16; ++k) zerov[k] = 0.0f;
    asm("" : "+v"(zerov));

    float rmin[16];
    #pragma unroll
    for (int k = 0; k < 16; ++k) rmin[k] = INFINITY;

    #pragma unroll 2
    for (int tile = 0; tile < NTILES; ++tile) {
        const bf16x8 bfrag = bp[tile * 64];         // 32 points * 2 halves
        f32x16 d = __builtin_amdgcn_mfma_f32_32x32x16_bf16(
            afrag, bfrag, zerov, 0, 0, 0);
        asm("" : "+v"(d));                          // keep D in ArchVGPRs
        #pragma unroll
        for (int k = 0; k < 16; ++k) rmin[k] = fminf(rmin[k], d[k]);
    }

    // Reduce over the 32 lanes (targets) sharing this kh; offsets <= 16 keep
    // the kh bit fixed.
    #pragma unroll
    for (int k = 0; k < 16; ++k) {
        #pragma unroll
        for (int off = 1; off <= 16; off <<= 1)
            rmin[k] = fminf(rmin[k], __shfl_xor(rmin[k], off));
    }
    if (lp == 0) {
        #pragma unroll
        for (int k = 0; k < 16; ++k) {
            int row = (k & 3) + 8 * (k >> 2) + 4 * kh;
            atomicMin(&keys[(size_t)b * NPTS + rb0 + wave * 32 + row],
                      enc_key(rmin[k]));
        }
    }

    // ---- completion: last block finalizes ----
    __threadfence();
    __syncthreads();
    __shared__ int lastflag;
    if (threadIdx.x == 0) {
        int old = __hip_atomic_fetch_add(done, 1, __ATOMIC_ACQ_REL,
                                         __HIP_MEMORY_SCOPE_AGENT);
        lastflag = (old == TOTALBLK - 1);
    }
    __syncthreads();
    if (!lastflag) return;

    __shared__ float red[BLOCK];
    for (int bb = 0; bb < BB; ++bb) {
        float s = 0.0f;
        for (int j = threadIdx.x; j < NPTS; j += BLOCK) {
            int kr = __hip_atomic_load(&rk[(size_t)bb * NPTS + j],
                                       __ATOMIC_RELAXED, __HIP_MEMORY_SCOPE_AGENT);
            int kc = __hip_atomic_load(&ck[(size_t)bb * NPTS + j],
                                       __ATOMIC_RELAXED, __HIP_MEMORY_SCOPE_AGENT);
            s += sqrtf(fmaxf(dec_key(kr), 0.0f)) + sqrtf(fmaxf(dec_key(kc), 0.0f));
        }
        red[threadIdx.x] = s;
        __syncthreads();
        for (int off = BLOCK / 2; off > 0; off >>= 1) {
            if (threadIdx.x < off) red[threadIdx.x] += red[threadIdx.x + off];
            __syncthreads();
        }
        if (threadIdx.x == 0) out[bb] = red[0] * (0.5f / (float)NPTS);
        __syncthreads();
    }
}

extern "C" void kernel_launch(void* const* d_in, const int* in_sizes, int n_in,
                              void* d_out, int out_size, void* d_ws, size_t ws_size,
                              hipStream_t stream) {
    const float* pred = (const float*)d_in[0];
    const float* tgtp = (const float*)d_in[1];
    float* out = (float*)d_out;

    // ws: pA 2MB | pB 2MB | rk 256KB | ck 256KB | done 4B
    char* ws = (char*)d_ws;
    unsigned short* pA = (unsigned short*)ws;
    unsigned short* pB = (unsigned short*)(ws + (size_t)NSIDE * 32);
    int* rk = (int*)(ws + (size_t)2 * NSIDE * 32);
    int* ck = rk + NSIDE;
    int* done = ck + NSIDE;

    chamfer_pack<<<NSIDE / BLOCK, BLOCK, 0, stream>>>(pred, tgtp, pA, pB,
                                                      rk, ck, out, done);

    // 4 t-chunks x 64 row-blocks x (8 batches x 2 dirs) = 4096 blocks.
    chamfer_mm<<<dim3(TCH, NRB, 16), BLOCK, 0, stream>>>(pA, pB, rk, ck, out, done);
}